// Round 15
// baseline (173.190 us; speedup 1.0000x reference)
//
#include <hip/hip_runtime.h>

#define N_ANCH 25200
#define NCLS   80
#define ROW    85
#define NIMG   16
#define KMAX   1024
#define NBINS  1024
#define CAND_CAP 4096
#define SC2_RPC 16                 // rows per chunk (25200 = 1575*16)
#define SC2_CPI 1575               // chunks per image
#define SC2_CFLOATS (SC2_RPC*ROW)  // 1360 floats = 5440 B
#define SC4_BPI 96                 // blocks per image (16*96 = 1536 = 6/CU)
#define SC4_WPI 192                // waves per image
#define PCHUNK 64                  // patch boxes per match block
#define CCNT_STRIDE 16             // ints; one 64B line per image counter

typedef unsigned long long u64;
typedef unsigned int u32;

// ---------------- ws layout (bytes) ----------------
#define OFF_KEYS 0ull                      // 16*25200*8 = 3,225,600 ; mask reuse (2 MB) after k_sort
#define OFF_HIST 3225600ull                // 16*1024*4 = 65,536
#define OFF_CCNT 3291136ull                // 16*64 = 1,024
#define OFF_CAND 3292160ull                // 16*4096*8 = 524,288 ; diag reuse ; pmax reuse
#define OFF_SEL  3816448ull                // 131,072
#define OFF_BOX  3947520ull                // 262,144
#define OFF_CLS  4209664ull                // 65,536
#define OFF_RINIT 4275200ull               // 2,048
#define OFF_KEEP 4277248ull                // 65,536
#define WS_NEED  4342784ull
#define ZERO_BYTES 66560ull                // hist + ccnt contiguous

__device__ __forceinline__ int key_bin(u64 key) {
    u32 hi = (u32)(key >> 32);
    if (hi == 0u) return 0;
    float conf = __uint_as_float(hi - 0x40000000u);
    int b = 1 + (int)(conf * 1022.0f);
    return b > 1023 ? 1023 : b;
}

__device__ __forceinline__ u64 readlane64(u64 v, int src) {
    u32 lo = (u32)__builtin_amdgcn_readlane((int)(u32)(v & 0xffffffffull), src);
    u32 hi = (u32)__builtin_amdgcn_readlane((int)(u32)(v >> 32), src);
    return ((u64)hi << 32) | (u64)lo;
}

__device__ __forceinline__ u64 shfl64_xor(u64 v, int m) {
    int lo = __shfl_xor((int)(u32)(v & 0xffffffffull), m, 64);
    int hi = __shfl_xor((int)(u32)(v >> 32), m, 64);
    return ((u64)(u32)hi << 32) | (u64)(u32)lo;
}

// ---- k_score v6: REGISTER-staged loads (deep vmem queue, not the shallow
// LDS-DMA queue), fA/fB dbuf, wave-private LDS bounce buffer, fused hist.
// __launch_bounds__(128,3) grants ~170 VGPR so the 48-reg staging never
// spills (round-12's failure mode: VGPR_Count=44 -> scratch, 285 MB moved).
__device__ __forceinline__ void ld6(const float* __restrict__ img, int ch, int lane,
                                    float4* f)
{
    const float4* s = (const float4*)(img + (size_t)ch * SC2_CFLOATS);
    f[0] = s[lane];
    f[1] = s[lane + 64];
    f[2] = s[lane + 128];
    f[3] = s[lane + 192];
    f[4] = s[lane + 256];
    if (lane < 20) f[5] = s[lane + 320];
}

__device__ __forceinline__ void st6(float* buf, int lane, const float4* f)
{
    float4* d = (float4*)buf;
    d[lane]       = f[0];
    d[lane + 64]  = f[1];
    d[lane + 128] = f[2];
    d[lane + 192] = f[3];
    d[lane + 256] = f[4];
    if (lane < 20) d[lane + 320] = f[5];
}

__device__ __forceinline__ void sc_compute(int b, int c, int lane, const float* buf,
                                           u64* __restrict__ keys, int* bh)
{
    const int r = lane & 15, h = lane >> 4;      // 4 lanes/row, 20 classes each
    const float* p = buf + r * ROW;
    const float obj = p[4];
    float best = -1.0f; int bc = 0;
    #pragma unroll
    for (int d = 0; d < 20; ++d) {
        const float s = p[5 + h * 20 + d] * obj;
        if (s > best) { best = s; bc = h * 20 + d; }
    }
    #pragma unroll
    for (int m = 16; m <= 32; m <<= 1) {
        const float o = __shfl_xor(best, m, 64);
        const int  oc = __shfl_xor(bc, m, 64);
        if (o > best || (o == best && oc < bc)) { best = o; bc = oc; }
    }
    if (h == 0) {
        const int n = c * SC2_RPC + r;
        const float th = (b < 8) ? 0.25f : 0.001f;
        const bool valid = (obj > th) && (best > th);
        const u32 hi = valid ? (__float_as_uint(best) + 0x40000000u) : 0u;
        if (valid) {
            int bin = 1 + (int)(best * 1022.0f);
            if (bin > 1023) bin = 1023;
            atomicAdd(&bh[bin], 1);
        }
        const u32 nbar = 32767u - (u32)n;
        keys[(size_t)b * N_ANCH + n] =
            ((u64)hi << 32) | ((u64)nbar << 8) | (u64)(u32)bc;
    }
}

__global__ __launch_bounds__(128, 3) void k_score(const float* __restrict__ clean,
                                                  const float* __restrict__ patch,
                                                  u64* __restrict__ keys,
                                                  int* __restrict__ hist)
{
    __shared__ float lds[2][SC2_CFLOATS];        // 10,880 B (wave-private bufs)
    __shared__ int bh[NBINS];                    // 4 KB -> 14.9 KB total
    const int t = threadIdx.x;
    const int wv = t >> 6, lane = t & 63;
    const int b = blockIdx.x / SC4_BPI;
    const int blk = blockIdx.x - b * SC4_BPI;
    const int wimg = blk * 2 + wv;               // 0..191
    for (int i = t; i < NBINS; i += 128) bh[i] = 0;
    __syncthreads();
    const float* img = (b < 8) ? clean + (size_t)b * N_ANCH * ROW
                               : patch + (size_t)(b - 8) * N_ANCH * ROW;
    float* buf = &lds[wv][0];
    float4 fA[6], fB[6];
    bool useA = true;
    ld6(img, wimg, lane, fA);
    for (int c = wimg; c < SC2_CPI; c += SC4_WPI) {
        const int cn = c + SC4_WPI;
        if (useA) {
            if (cn < SC2_CPI) ld6(img, cn, lane, fB);   // next chunk in flight
            st6(buf, lane, fA);                         // waits only on fA's loads
        } else {
            if (cn < SC2_CPI) ld6(img, cn, lane, fA);
            st6(buf, lane, fB);
        }
        sc_compute(b, c, lane, buf, keys, bh);          // same-wave LDS is in-order
        useA = !useA;
    }
    __syncthreads();
    for (int i = t; i < NBINS; i += 128)
        if (bh[i]) atomicAdd(&hist[b * NBINS + i], bh[i]);
}

// K4 (+fused threshold): each block recomputes T from hist via LDS suffix scan,
// then wave-aggregated compaction of its 1575-key stripe.
__global__ __launch_bounds__(256) void k_compact(const u64* __restrict__ keys,
                                                 const int* __restrict__ hist,
                                                 int* __restrict__ ccnt,
                                                 u64* __restrict__ cand)
{
    __shared__ int arr[256];
    __shared__ int Tsh;
    const int b = blockIdx.x;
    const int t = threadIdx.x;
    const int K = (b < 8) ? 256 : 1024;
    int hh[4];
    hh[0] = hist[b * NBINS + 4 * t + 0];
    hh[1] = hist[b * NBINS + 4 * t + 1];
    hh[2] = hist[b * NBINS + 4 * t + 2];
    hh[3] = hist[b * NBINS + 4 * t + 3];
    const int r = hh[0] + hh[1] + hh[2] + hh[3];
    arr[t] = r;
    __syncthreads();
    for (int off = 1; off < 256; off <<= 1) {
        int v = (t + off < 256) ? arr[t + off] : 0;
        __syncthreads();
        arr[t] += v;
        __syncthreads();
    }
    int cb = arr[t] - r;
    for (int d = 3; d >= 0; --d) {
        int ca = cb + hh[d];
        if (cb < K && ca >= K) Tsh = 4 * t + d;   // unique (suffix monotone)
        cb = ca;
    }
    __syncthreads();
    const int T = Tsh;
    const u64* kp = keys + (size_t)b * N_ANCH;
    const int start = blockIdx.y * 1575;
    const int lane = t & 63;
    #pragma unroll
    for (int it = 0; it < 7; ++it) {
        const int off = it * 256 + t;                    // 0..1791
        const bool in = off < 1575;
        const u64 key = in ? kp[start + off] : 0ull;
        const bool cnd = in && (key_bin(key) >= T);
        const u64 bal = __ballot(cnd);
        if (bal) {
            int base = 0;
            if (lane == 0) base = atomicAdd(&ccnt[b * CCNT_STRIDE], __popcll(bal));
            base = __shfl(base, 0, 64);
            if (cnd) {
                const int pos = base + __popcll(bal & ((1ull << lane) - 1ull));
                if (pos < CAND_CAP) cand[(size_t)b * CAND_CAP + pos] = key;
            }
        }
    }
}

// K5: per-image bitonic sort (descending), hybrid register/shuffle/LDS
__global__ __launch_bounds__(1024) void k_sort(const u64* __restrict__ cand,
                                               const int* __restrict__ ccnt,
                                               u64* __restrict__ sel)
{
    __shared__ u64 sk[CAND_CAP];   // 32 KB
    const int b = blockIdx.x;
    const int C = min(ccnt[b * CCNT_STRIDE], CAND_CAP);
    const int t = threadIdx.x;
    u64 e0, e1, e2, e3;
    e0 = (t < C) ? cand[(size_t)b * CAND_CAP + t] : 0ull;
    e1 = (1024 + t < C) ? cand[(size_t)b * CAND_CAP + 1024 + t] : 0ull;
    e2 = (2048 + t < C) ? cand[(size_t)b * CAND_CAP + 2048 + t] : 0ull;
    e3 = (3072 + t < C) ? cand[(size_t)b * CAND_CAP + 3072 + t] : 0ull;
    #define CSWAP_D(a, c) { if ((a) < (c)) { u64 _t = (a); (a) = (c); (c) = _t; } }
    #define CSWAP_A(a, c) { if ((a) > (c)) { u64 _t = (a); (a) = (c); (c) = _t; } }
    for (int k = 2; k <= 4096; k <<= 1) {
        for (int j = k >> 1; j > 0; j >>= 1) {
            if (j >= 1024) {
                if (j == 2048) { CSWAP_D(e0, e2); CSWAP_D(e1, e3); }
                else {
                    if (k == 4096) { CSWAP_D(e0, e1); CSWAP_D(e2, e3); }
                    else           { CSWAP_D(e0, e1); CSWAP_A(e2, e3); }
                }
            } else if (j >= 64) {
                __syncthreads();
                sk[t] = e0; sk[1024 + t] = e1; sk[2048 + t] = e2; sk[3072 + t] = e3;
                __syncthreads();
                const int tp = t ^ j;
                #pragma unroll
                for (int p = 0; p < 4; ++p) {
                    const int i = p * 1024 + t;
                    const u64 cv = (p == 0) ? e0 : (p == 1) ? e1 : (p == 2) ? e2 : e3;
                    const u64 o = sk[p * 1024 + tp];
                    const bool take_max = (((i & k) == 0) == ((t & j) == 0));
                    const u64 mx = cv > o ? cv : o;
                    const u64 mn = cv > o ? o : cv;
                    const u64 nv = take_max ? mx : mn;
                    if (p == 0) e0 = nv; else if (p == 1) e1 = nv;
                    else if (p == 2) e2 = nv; else e3 = nv;
                }
            } else {
                #pragma unroll
                for (int p = 0; p < 4; ++p) {
                    const int i = p * 1024 + t;
                    const u64 cv = (p == 0) ? e0 : (p == 1) ? e1 : (p == 2) ? e2 : e3;
                    const u64 o = shfl64_xor(cv, j);
                    const bool take_max = (((i & k) == 0) == ((t & j) == 0));
                    const u64 mx = cv > o ? cv : o;
                    const u64 mn = cv > o ? o : cv;
                    const u64 nv = take_max ? mx : mn;
                    if (p == 0) e0 = nv; else if (p == 1) e1 = nv;
                    else if (p == 2) e2 = nv; else e3 = nv;
                }
            }
        }
    }
    const int K = (b < 8) ? 256 : 1024;
    if (t < K) sel[b * KMAX + t] = e0;
    #undef CSWAP_D
    #undef CSWAP_A
}

// K6+K7a fused: decode sel -> LDS boxes; y==0 writes boxes/cls/rinit; mask stripe + diag
__global__ __launch_bounds__(1024) void k_nms_mask(const float* __restrict__ clean,
                                                   const float* __restrict__ patch,
                                                   const u64* __restrict__ sel,
                                                   float4* __restrict__ boxes,
                                                   int* __restrict__ cls,
                                                   u64* __restrict__ rinit,
                                                   u64* __restrict__ mask,
                                                   u64* __restrict__ diag)
{
    __shared__ float4 bx[KMAX];
    __shared__ float ar[KMAX];
    const int b = blockIdx.x, y = blockIdx.y;
    const int K = (b < 8) ? 256 : 1024;
    const int row0 = y * 64;
    if (row0 >= K) return;                  // block-uniform
    const int t = threadIdx.x;
    {
        const u64 key = (t < K) ? sel[b * KMAX + t] : 0ull;
        const u32 hi = (u32)(key >> 32);
        const bool valid = (t < K) && (hi != 0u);
        const u64 bal = __ballot(valid);
        if (y == 0 && (t & 63) == 0) rinit[b * 16 + (t >> 6)] = ~bal;
        if (t < K) {
            const int n = 32767 - (int)((key >> 8) & 0x7FFFu);
            const int c = (int)(key & 0x7Fu);
            const float* src = ((b < 8) ? (clean + (size_t)b * N_ANCH * ROW)
                                        : (patch + (size_t)(b - 8) * N_ANCH * ROW))
                               + (size_t)n * ROW;
            const float x = src[0], yy = src[1], w = src[2], h = src[3];
            const float4 raw = make_float4(x - w * 0.5f, yy - h * 0.5f,
                                           x + w * 0.5f, yy + h * 0.5f);
            if (y == 0) { boxes[b * KMAX + t] = raw; cls[b * KMAX + t] = c; }
            const float off = (float)c * 4096.0f;
            const float4 ob = make_float4(raw.x + off, raw.y + off,
                                          raw.z + off, raw.w + off);
            bx[t] = ob;
            ar[t] = (ob.z - ob.x) * (ob.w - ob.y);
        }
    }
    __syncthreads();
    const int w   = t >> 6;
    const int row = row0 + (t & 63);
    u64* dst = mask + ((size_t)b * KMAX + row) * 16 + w;
    if (((w << 6) + 63) <= row0 && row0 > 0) { *dst = 0ull; return; }
    const float4 bi = bx[row];
    const float ai = ar[row];
    const int jbase = w << 6;
    u64 m = 0;
    #pragma unroll 8
    for (int k = 0; k < 64; ++k) {
        const int j = jbase + k;
        const float4 bj = bx[j];
        const float ax = fmaxf(bi.x, bj.x), ay = fmaxf(bi.y, bj.y);
        const float bx2 = fminf(bi.z, bj.z), by2 = fminf(bi.w, bj.w);
        const float iw = fmaxf(bx2 - ax, 0.f), ih = fmaxf(by2 - ay, 0.f);
        const float inter = iw * ih;
        const float iou = inter / (ai + ar[j] - inter);
        if (j > row && iou > 0.45f) m |= (1ull << k);
    }
    *dst = m;
    if (w == (row0 >> 6)) diag[(size_t)b * KMAX + row] = m;
}

// K7b: greedy scan (sparse chain + ILP), one block per image
__global__ __launch_bounds__(1024) void k_nms_scan(const u64* __restrict__ mask,
                                                   const u64* __restrict__ diag,
                                                   const u64* __restrict__ rinit,
                                                   int* __restrict__ keep)
{
    extern __shared__ u64 smem[];           // K*16 mask + K diag
    const int b = blockIdx.x;
    const int K = (b < 8) ? 256 : 1024;
    const int W = K >> 6;
    const int t = threadIdx.x;
    u64* smask = smem;
    u64* sdiag = smem + (size_t)K * 16;
    {
        const float4* s4 = (const float4*)(mask + (size_t)b * KMAX * 16);
        float4* d4 = (float4*)smask;
        const int n4 = (K * 16) >> 1;
        for (int i = t; i < n4; i += 1024) d4[i] = s4[i];
        const float4* s4d = (const float4*)(diag + (size_t)b * KMAX);
        float4* d4d = (float4*)sdiag;
        for (int i = t; i < (K >> 1); i += 1024) d4d[i] = s4d[i];
    }
    __syncthreads();
    if (t >= 64) return;
    const int lane = t;
    const int q = lane >> 4;
    const int wl = lane & 15;
    u64 w_remv = rinit[b * 16 + wl];
    u64 ow = readlane64(w_remv, 0);
    u64 dj = sdiag[lane];
    for (int g = 0; g < W; ++g) {
        u64 nz = __ballot(dj != 0ull);
        u64 o = ow;
        while (nz) {
            const int j = (int)__builtin_ctzll(nz);
            nz &= nz - 1;
            if (!((o >> j) & 1ull)) o |= readlane64(dj, j);
        }
        const u64 kept = ~o;
        if (g + 1 < W) dj = sdiag[(g + 1) * 64 + lane];
        const u64* mrow = smask + (size_t)(g * 64 + q * 16) * 16 + wl;
        const u32 kg = (u32)((kept >> (q * 16)) & 0xFFFFull);
        u64 a0 = 0, a1 = 0;
        #pragma unroll
        for (int i = 0; i < 16; i += 2) {
            const u64 m0 = mrow[(size_t)(i + 0) * 16];
            const u64 m1 = mrow[(size_t)(i + 1) * 16];
            a0 |= ((kg >> i) & 1u) ? m0 : 0ull;
            a1 |= ((kg >> (i + 1)) & 1u) ? m1 : 0ull;
        }
        u64 part = a0 | a1;
        part |= shfl64_xor(part, 16);
        part |= shfl64_xor(part, 32);
        w_remv |= part;
        if (g + 1 < W) ow = readlane64(w_remv, g + 1);
    }
    if (lane < W) {
        #pragma unroll
        for (int k = 0; k < 64; ++k)
            keep[b * KMAX + lane * 64 + k] = (int)(((w_remv >> k) & 1) ^ 1ull);
    }
}

// K8a: partial max IoU: block = (clean image, patch chunk of 64)
__global__ __launch_bounds__(256) void k_match_partial(const float4* __restrict__ boxes,
                                                       const int* __restrict__ cls,
                                                       const int* __restrict__ keep,
                                                       float* __restrict__ pmax)
{
    __shared__ float4 pb[PCHUNK];
    __shared__ float par[PCHUNK];
    __shared__ int pcls[PCHUNK];
    const int c = blockIdx.x;
    const int p = blockIdx.y;
    const int bp = 8 + c;
    const int t = threadIdx.x;
    if (t < PCHUNK) {
        const int i = p * PCHUNK + t;
        const float4 v = boxes[bp * KMAX + i];
        pb[t] = v;
        par[t] = (v.z - v.x) * (v.w - v.y);
        pcls[t] = keep[bp * KMAX + i] ? cls[bp * KMAX + i] : -1;
    }
    __syncthreads();
    const float4 bc = boxes[c * KMAX + t];
    const int cc = cls[c * KMAX + t];
    const float area_c = (bc.z - bc.x) * (bc.w - bc.y);
    float tm = 0.f;
    #pragma unroll 8
    for (int i = 0; i < PCHUNK; ++i) {
        const float4 bi = pb[i];
        const float ax = fmaxf(bi.x, bc.x), ay = fmaxf(bi.y, bc.y);
        const float bx2 = fminf(bi.z, bc.z), by2 = fminf(bi.w, bc.w);
        const float iw = fmaxf(bx2 - ax, 0.f), ih = fmaxf(by2 - ay, 0.f);
        const float inter = iw * ih;
        const float iou = inter / (par[i] + area_c - inter);
        tm = fmaxf(tm, (pcls[i] == cc) ? iou : 0.f);
    }
    pmax[(c * 16 + p) * 256 + t] = tm;
}

// K8b+K9 fused: one block reduces all 8 clean images + writes the scalar
__global__ __launch_bounds__(256) void k_match_final(const float* __restrict__ pmax,
                                                     const int* __restrict__ keep,
                                                     float* __restrict__ out)
{
    __shared__ float red[8];
    const int t = threadIdx.x;
    float tot = 0.f, cn = 0.f;
    for (int c = 0; c < 8; ++c) {
        float tm = 0.f;
        #pragma unroll
        for (int p = 0; p < 16; ++p)
            tm = fmaxf(tm, pmax[(c * 16 + p) * 256 + t]);
        const int kc = keep[c * KMAX + t];
        float val = kc ? tm : 0.f;
        float cv  = kc ? 1.f : 0.f;
        for (int off = 32; off > 0; off >>= 1) {
            val += __shfl_down(val, off);
            cv  += __shfl_down(cv, off);
        }
        const int wv = t >> 6, lane = t & 63;
        if (lane == 0) { red[wv] = val; red[4 + wv] = cv; }
        __syncthreads();
        if (t == 0) {
            tot += red[0] + red[1] + red[2] + red[3];
            cn  += red[4] + red[5] + red[6] + red[7];
        }
        __syncthreads();
    }
    if (t == 0)
        out[0] = (cn > 0.f) ? (1.0f - tot / fmaxf(cn, 1.0f)) : 1.0f;
}

extern "C" void kernel_launch(void* const* d_in, const int* in_sizes, int n_in,
                              void* d_out, int out_size, void* d_ws, size_t ws_size,
                              hipStream_t stream)
{
    if (ws_size < WS_NEED) return;
    const float* clean = (const float*)d_in[0];
    const float* patch = (const float*)d_in[1];
    float* out = (float*)d_out;
    char* ws = (char*)d_ws;

    u64*    keys = (u64*)(ws + OFF_KEYS);
    u64*    mask = (u64*)(ws + OFF_KEYS);   // reuse after k_sort
    int*    hist = (int*)(ws + OFF_HIST);
    int*    ccnt = (int*)(ws + OFF_CCNT);
    u64*    cand = (u64*)(ws + OFF_CAND);
    u64*    diag = (u64*)(ws + OFF_CAND);   // reuse after k_sort
    float*  pmax = (float*)(ws + OFF_CAND); // reuse after k_nms_scan
    u64*    sel  = (u64*)(ws + OFF_SEL);
    float4* boxes = (float4*)(ws + OFF_BOX);
    int*    cls  = (int*)(ws + OFF_CLS);
    u64*    rinit = (u64*)(ws + OFF_RINIT);
    int*    keep = (int*)(ws + OFF_KEEP);

    hipMemsetAsync(ws + OFF_HIST, 0, ZERO_BYTES, stream);

    k_score<<<NIMG * SC4_BPI, 128, 0, stream>>>(clean, patch, keys, hist);
    k_compact<<<dim3(NIMG, 16), 256, 0, stream>>>(keys, hist, ccnt, cand);
    k_sort<<<NIMG, 1024, 0, stream>>>(cand, ccnt, sel);
    k_nms_mask<<<dim3(NIMG, 16), 1024, 0, stream>>>(clean, patch, sel, boxes, cls,
                                                    rinit, mask, diag);
    k_nms_scan<<<NIMG, 1024, KMAX * 16 * 8 + KMAX * 8, stream>>>(mask, diag, rinit, keep);
    k_match_partial<<<dim3(8, 16), 256, 0, stream>>>(boxes, cls, keep, pmax);
    k_match_final<<<1, 256, 0, stream>>>(pmax, keep, out);
}

// Round 16
// 132.339 us; speedup vs baseline: 1.3087x; 1.3087x over previous
//
#include <hip/hip_runtime.h>

#define N_ANCH 25200
#define NCLS   80
#define ROW    85
#define NIMG   16
#define KMAX   1024
#define NBINS  1024
#define CAND_CAP 4096
#define SC2_RPC 16                 // rows per chunk (25200 = 1575*16)
#define SC2_CPI 1575               // chunks per image
#define SC2_CFLOATS (SC2_RPC*ROW)  // 1360 floats = 5440 B = 340 float4 (divides exactly)
#define SC4_BPI 96                 // blocks per image (16*96 = 1536 = 6/CU)
#define SC4_WPI 192                // waves per image
#define PCHUNK 64                  // patch boxes per match block
#define CCNT_STRIDE 16             // ints; one 64B line per image counter

typedef unsigned long long u64;
typedef unsigned int u32;

// ---------------- ws layout (bytes) ----------------
#define OFF_KEYS 0ull                      // 16*25200*8 = 3,225,600 ; mask reuse (2 MB) after k_sort
#define OFF_HIST 3225600ull                // 16*1024*4 = 65,536
#define OFF_CCNT 3291136ull                // 16*64 = 1,024
#define OFF_CAND 3292160ull                // 16*4096*8 = 524,288 ; diag reuse ; pmax reuse
#define OFF_SEL  3816448ull                // 131,072
#define OFF_BOX  3947520ull                // 262,144
#define OFF_CLS  4209664ull                // 65,536
#define OFF_RINIT 4275200ull               // 2,048
#define OFF_KEEP 4277248ull                // 65,536
#define WS_NEED  4342784ull
#define ZERO_BYTES 66560ull                // hist + ccnt contiguous

__device__ __forceinline__ int key_bin(u64 key) {
    u32 hi = (u32)(key >> 32);
    if (hi == 0u) return 0;
    float conf = __uint_as_float(hi - 0x40000000u);
    int b = 1 + (int)(conf * 1022.0f);
    return b > 1023 ? 1023 : b;
}

__device__ __forceinline__ u64 readlane64(u64 v, int src) {
    u32 lo = (u32)__builtin_amdgcn_readlane((int)(u32)(v & 0xffffffffull), src);
    u32 hi = (u32)__builtin_amdgcn_readlane((int)(u32)(v >> 32), src);
    return ((u64)hi << 32) | (u64)lo;
}

__device__ __forceinline__ u64 shfl64_xor(u64 v, int m) {
    int lo = __shfl_xor((int)(u32)(v & 0xffffffffull), m, 64);
    int hi = __shfl_xor((int)(u32)(v >> 32), m, 64);
    return ((u64)(u32)hi << 32) | (u64)(u32)lo;
}

// ---- k_score v7: SCALARIZED register staging (no arrays -> no scratch).
// Named float4 a0..a5 / b0..b5, macro-inlined loads/stores, manual A/B
// unroll (no register copies). 16-row chunks divide the image exactly,
// so every load is in-bounds with no clamping.
#define SC_LOAD6(v0, v1, v2, v3, v4, v5, ch) {                                \
    const float4* _s = (const float4*)(img + (size_t)(ch) * SC2_CFLOATS);     \
    v0 = _s[lane];       v1 = _s[lane + 64];  v2 = _s[lane + 128];            \
    v3 = _s[lane + 192]; v4 = _s[lane + 256];                                 \
    if (lane < 20) v5 = _s[lane + 320];                                       \
}
#define SC_STORE6(v0, v1, v2, v3, v4, v5) {                                   \
    float4* _d = (float4*)buf;                                                \
    _d[lane] = v0;       _d[lane + 64] = v1;  _d[lane + 128] = v2;            \
    _d[lane + 192] = v3; _d[lane + 256] = v4;                                 \
    if (lane < 20) _d[lane + 320] = v5;                                       \
}

__device__ __forceinline__ void sc_compute(int b, int c, int lane, const float* buf,
                                           u64* __restrict__ keys, int* bh)
{
    const int r = lane & 15, h = lane >> 4;      // 4 lanes/row, 20 classes each
    const float* p = buf + r * ROW;
    const float obj = p[4];
    float best = -1.0f; int bc = 0;
    #pragma unroll
    for (int d = 0; d < 20; ++d) {
        const float s = p[5 + h * 20 + d] * obj;
        if (s > best) { best = s; bc = h * 20 + d; }
    }
    #pragma unroll
    for (int m = 16; m <= 32; m <<= 1) {
        const float o = __shfl_xor(best, m, 64);
        const int  oc = __shfl_xor(bc, m, 64);
        if (o > best || (o == best && oc < bc)) { best = o; bc = oc; }
    }
    if (h == 0) {
        const int n = c * SC2_RPC + r;
        const float th = (b < 8) ? 0.25f : 0.001f;
        const bool valid = (obj > th) && (best > th);
        const u32 hi = valid ? (__float_as_uint(best) + 0x40000000u) : 0u;
        if (valid) {
            int bin = 1 + (int)(best * 1022.0f);
            if (bin > 1023) bin = 1023;
            atomicAdd(&bh[bin], 1);
        }
        const u32 nbar = 32767u - (u32)n;
        keys[(size_t)b * N_ANCH + n] =
            ((u64)hi << 32) | ((u64)nbar << 8) | (u64)(u32)bc;
    }
}

__global__ __launch_bounds__(128, 3) void k_score(const float* __restrict__ clean,
                                                  const float* __restrict__ patch,
                                                  u64* __restrict__ keys,
                                                  int* __restrict__ hist)
{
    __shared__ float lds[2][SC2_CFLOATS];        // 10,880 B (wave-private bufs)
    __shared__ int bh[NBINS];                    // 4 KB -> 14.9 KB total
    const int t = threadIdx.x;
    const int wv = t >> 6, lane = t & 63;
    const int b = blockIdx.x / SC4_BPI;
    const int blk = blockIdx.x - b * SC4_BPI;
    const int wimg = blk * 2 + wv;               // 0..191
    for (int i = t; i < NBINS; i += 128) bh[i] = 0;
    __syncthreads();
    const float* img = (b < 8) ? clean + (size_t)b * N_ANCH * ROW
                               : patch + (size_t)(b - 8) * N_ANCH * ROW;
    float* buf = &lds[wv][0];
    float4 a0, a1, a2, a3, a4, a5, b0, b1, b2, b3, b4, b5;
    a5 = make_float4(0.f, 0.f, 0.f, 0.f);
    b5 = make_float4(0.f, 0.f, 0.f, 0.f);
    int c = wimg;
    SC_LOAD6(a0, a1, a2, a3, a4, a5, c);
    while (c < SC2_CPI) {
        int cn = c + SC4_WPI;
        if (cn < SC2_CPI) SC_LOAD6(b0, b1, b2, b3, b4, b5, cn);   // next in flight
        SC_STORE6(a0, a1, a2, a3, a4, a5);                        // waits only on A
        sc_compute(b, c, lane, buf, keys, bh);
        c = cn;
        if (c >= SC2_CPI) break;
        cn = c + SC4_WPI;
        if (cn < SC2_CPI) SC_LOAD6(a0, a1, a2, a3, a4, a5, cn);
        SC_STORE6(b0, b1, b2, b3, b4, b5);
        sc_compute(b, c, lane, buf, keys, bh);
        c = cn;
    }
    __syncthreads();
    for (int i = t; i < NBINS; i += 128)
        if (bh[i]) atomicAdd(&hist[b * NBINS + i], bh[i]);
}

// K4 (+fused threshold): each block recomputes T from hist via LDS suffix scan,
// then wave-aggregated compaction of its 1575-key stripe.
__global__ __launch_bounds__(256) void k_compact(const u64* __restrict__ keys,
                                                 const int* __restrict__ hist,
                                                 int* __restrict__ ccnt,
                                                 u64* __restrict__ cand)
{
    __shared__ int arr[256];
    __shared__ int Tsh;
    const int b = blockIdx.x;
    const int t = threadIdx.x;
    const int K = (b < 8) ? 256 : 1024;
    int hh[4];
    hh[0] = hist[b * NBINS + 4 * t + 0];
    hh[1] = hist[b * NBINS + 4 * t + 1];
    hh[2] = hist[b * NBINS + 4 * t + 2];
    hh[3] = hist[b * NBINS + 4 * t + 3];
    const int r = hh[0] + hh[1] + hh[2] + hh[3];
    arr[t] = r;
    __syncthreads();
    for (int off = 1; off < 256; off <<= 1) {
        int v = (t + off < 256) ? arr[t + off] : 0;
        __syncthreads();
        arr[t] += v;
        __syncthreads();
    }
    int cb = arr[t] - r;
    for (int d = 3; d >= 0; --d) {
        int ca = cb + hh[d];
        if (cb < K && ca >= K) Tsh = 4 * t + d;   // unique (suffix monotone)
        cb = ca;
    }
    __syncthreads();
    const int T = Tsh;
    const u64* kp = keys + (size_t)b * N_ANCH;
    const int start = blockIdx.y * 1575;
    const int lane = t & 63;
    #pragma unroll
    for (int it = 0; it < 7; ++it) {
        const int off = it * 256 + t;                    // 0..1791
        const bool in = off < 1575;
        const u64 key = in ? kp[start + off] : 0ull;
        const bool cnd = in && (key_bin(key) >= T);
        const u64 bal = __ballot(cnd);
        if (bal) {
            int base = 0;
            if (lane == 0) base = atomicAdd(&ccnt[b * CCNT_STRIDE], __popcll(bal));
            base = __shfl(base, 0, 64);
            if (cnd) {
                const int pos = base + __popcll(bal & ((1ull << lane) - 1ull));
                if (pos < CAND_CAP) cand[(size_t)b * CAND_CAP + pos] = key;
            }
        }
    }
}

// K5: per-image bitonic sort (descending), hybrid register/shuffle/LDS
__global__ __launch_bounds__(1024) void k_sort(const u64* __restrict__ cand,
                                               const int* __restrict__ ccnt,
                                               u64* __restrict__ sel)
{
    __shared__ u64 sk[CAND_CAP];   // 32 KB
    const int b = blockIdx.x;
    const int C = min(ccnt[b * CCNT_STRIDE], CAND_CAP);
    const int t = threadIdx.x;
    u64 e0, e1, e2, e3;
    e0 = (t < C) ? cand[(size_t)b * CAND_CAP + t] : 0ull;
    e1 = (1024 + t < C) ? cand[(size_t)b * CAND_CAP + 1024 + t] : 0ull;
    e2 = (2048 + t < C) ? cand[(size_t)b * CAND_CAP + 2048 + t] : 0ull;
    e3 = (3072 + t < C) ? cand[(size_t)b * CAND_CAP + 3072 + t] : 0ull;
    #define CSWAP_D(a, c) { if ((a) < (c)) { u64 _t = (a); (a) = (c); (c) = _t; } }
    #define CSWAP_A(a, c) { if ((a) > (c)) { u64 _t = (a); (a) = (c); (c) = _t; } }
    for (int k = 2; k <= 4096; k <<= 1) {
        for (int j = k >> 1; j > 0; j >>= 1) {
            if (j >= 1024) {
                if (j == 2048) { CSWAP_D(e0, e2); CSWAP_D(e1, e3); }
                else {
                    if (k == 4096) { CSWAP_D(e0, e1); CSWAP_D(e2, e3); }
                    else           { CSWAP_D(e0, e1); CSWAP_A(e2, e3); }
                }
            } else if (j >= 64) {
                __syncthreads();
                sk[t] = e0; sk[1024 + t] = e1; sk[2048 + t] = e2; sk[3072 + t] = e3;
                __syncthreads();
                const int tp = t ^ j;
                #pragma unroll
                for (int p = 0; p < 4; ++p) {
                    const int i = p * 1024 + t;
                    const u64 cv = (p == 0) ? e0 : (p == 1) ? e1 : (p == 2) ? e2 : e3;
                    const u64 o = sk[p * 1024 + tp];
                    const bool take_max = (((i & k) == 0) == ((t & j) == 0));
                    const u64 mx = cv > o ? cv : o;
                    const u64 mn = cv > o ? o : cv;
                    const u64 nv = take_max ? mx : mn;
                    if (p == 0) e0 = nv; else if (p == 1) e1 = nv;
                    else if (p == 2) e2 = nv; else e3 = nv;
                }
            } else {
                #pragma unroll
                for (int p = 0; p < 4; ++p) {
                    const int i = p * 1024 + t;
                    const u64 cv = (p == 0) ? e0 : (p == 1) ? e1 : (p == 2) ? e2 : e3;
                    const u64 o = shfl64_xor(cv, j);
                    const bool take_max = (((i & k) == 0) == ((t & j) == 0));
                    const u64 mx = cv > o ? cv : o;
                    const u64 mn = cv > o ? o : cv;
                    const u64 nv = take_max ? mx : mn;
                    if (p == 0) e0 = nv; else if (p == 1) e1 = nv;
                    else if (p == 2) e2 = nv; else e3 = nv;
                }
            }
        }
    }
    const int K = (b < 8) ? 256 : 1024;
    if (t < K) sel[b * KMAX + t] = e0;
    #undef CSWAP_D
    #undef CSWAP_A
}

// K6+K7a fused: decode sel -> LDS boxes; y==0 writes boxes/cls/rinit; mask stripe + diag
__global__ __launch_bounds__(1024) void k_nms_mask(const float* __restrict__ clean,
                                                   const float* __restrict__ patch,
                                                   const u64* __restrict__ sel,
                                                   float4* __restrict__ boxes,
                                                   int* __restrict__ cls,
                                                   u64* __restrict__ rinit,
                                                   u64* __restrict__ mask,
                                                   u64* __restrict__ diag)
{
    __shared__ float4 bx[KMAX];
    __shared__ float ar[KMAX];
    const int b = blockIdx.x, y = blockIdx.y;
    const int K = (b < 8) ? 256 : 1024;
    const int row0 = y * 64;
    if (row0 >= K) return;                  // block-uniform
    const int t = threadIdx.x;
    {
        const u64 key = (t < K) ? sel[b * KMAX + t] : 0ull;
        const u32 hi = (u32)(key >> 32);
        const bool valid = (t < K) && (hi != 0u);
        const u64 bal = __ballot(valid);
        if (y == 0 && (t & 63) == 0) rinit[b * 16 + (t >> 6)] = ~bal;
        if (t < K) {
            const int n = 32767 - (int)((key >> 8) & 0x7FFFu);
            const int c = (int)(key & 0x7Fu);
            const float* src = ((b < 8) ? (clean + (size_t)b * N_ANCH * ROW)
                                        : (patch + (size_t)(b - 8) * N_ANCH * ROW))
                               + (size_t)n * ROW;
            const float x = src[0], yy = src[1], w = src[2], h = src[3];
            const float4 raw = make_float4(x - w * 0.5f, yy - h * 0.5f,
                                           x + w * 0.5f, yy + h * 0.5f);
            if (y == 0) { boxes[b * KMAX + t] = raw; cls[b * KMAX + t] = c; }
            const float off = (float)c * 4096.0f;
            const float4 ob = make_float4(raw.x + off, raw.y + off,
                                          raw.z + off, raw.w + off);
            bx[t] = ob;
            ar[t] = (ob.z - ob.x) * (ob.w - ob.y);
        }
    }
    __syncthreads();
    const int w   = t >> 6;
    const int row = row0 + (t & 63);
    u64* dst = mask + ((size_t)b * KMAX + row) * 16 + w;
    if (((w << 6) + 63) <= row0 && row0 > 0) { *dst = 0ull; return; }
    const float4 bi = bx[row];
    const float ai = ar[row];
    const int jbase = w << 6;
    u64 m = 0;
    #pragma unroll 8
    for (int k = 0; k < 64; ++k) {
        const int j = jbase + k;
        const float4 bj = bx[j];
        const float ax = fmaxf(bi.x, bj.x), ay = fmaxf(bi.y, bj.y);
        const float bx2 = fminf(bi.z, bj.z), by2 = fminf(bi.w, bj.w);
        const float iw = fmaxf(bx2 - ax, 0.f), ih = fmaxf(by2 - ay, 0.f);
        const float inter = iw * ih;
        const float iou = inter / (ai + ar[j] - inter);
        if (j > row && iou > 0.45f) m |= (1ull << k);
    }
    *dst = m;
    if (w == (row0 >> 6)) diag[(size_t)b * KMAX + row] = m;
}

// K7b: greedy scan (sparse chain + ILP), one block per image
__global__ __launch_bounds__(1024) void k_nms_scan(const u64* __restrict__ mask,
                                                   const u64* __restrict__ diag,
                                                   const u64* __restrict__ rinit,
                                                   int* __restrict__ keep)
{
    extern __shared__ u64 smem[];           // K*16 mask + K diag
    const int b = blockIdx.x;
    const int K = (b < 8) ? 256 : 1024;
    const int W = K >> 6;
    const int t = threadIdx.x;
    u64* smask = smem;
    u64* sdiag = smem + (size_t)K * 16;
    {
        const float4* s4 = (const float4*)(mask + (size_t)b * KMAX * 16);
        float4* d4 = (float4*)smask;
        const int n4 = (K * 16) >> 1;
        for (int i = t; i < n4; i += 1024) d4[i] = s4[i];
        const float4* s4d = (const float4*)(diag + (size_t)b * KMAX);
        float4* d4d = (float4*)sdiag;
        for (int i = t; i < (K >> 1); i += 1024) d4d[i] = s4d[i];
    }
    __syncthreads();
    if (t >= 64) return;
    const int lane = t;
    const int q = lane >> 4;
    const int wl = lane & 15;
    u64 w_remv = rinit[b * 16 + wl];
    u64 ow = readlane64(w_remv, 0);
    u64 dj = sdiag[lane];
    for (int g = 0; g < W; ++g) {
        u64 nz = __ballot(dj != 0ull);
        u64 o = ow;
        while (nz) {
            const int j = (int)__builtin_ctzll(nz);
            nz &= nz - 1;
            if (!((o >> j) & 1ull)) o |= readlane64(dj, j);
        }
        const u64 kept = ~o;
        if (g + 1 < W) dj = sdiag[(g + 1) * 64 + lane];
        const u64* mrow = smask + (size_t)(g * 64 + q * 16) * 16 + wl;
        const u32 kg = (u32)((kept >> (q * 16)) & 0xFFFFull);
        u64 a0 = 0, a1 = 0;
        #pragma unroll
        for (int i = 0; i < 16; i += 2) {
            const u64 m0 = mrow[(size_t)(i + 0) * 16];
            const u64 m1 = mrow[(size_t)(i + 1) * 16];
            a0 |= ((kg >> i) & 1u) ? m0 : 0ull;
            a1 |= ((kg >> (i + 1)) & 1u) ? m1 : 0ull;
        }
        u64 part = a0 | a1;
        part |= shfl64_xor(part, 16);
        part |= shfl64_xor(part, 32);
        w_remv |= part;
        if (g + 1 < W) ow = readlane64(w_remv, g + 1);
    }
    if (lane < W) {
        #pragma unroll
        for (int k = 0; k < 64; ++k)
            keep[b * KMAX + lane * 64 + k] = (int)(((w_remv >> k) & 1) ^ 1ull);
    }
}

// K8a: partial max IoU: block = (clean image, patch chunk of 64)
__global__ __launch_bounds__(256) void k_match_partial(const float4* __restrict__ boxes,
                                                       const int* __restrict__ cls,
                                                       const int* __restrict__ keep,
                                                       float* __restrict__ pmax)
{
    __shared__ float4 pb[PCHUNK];
    __shared__ float par[PCHUNK];
    __shared__ int pcls[PCHUNK];
    const int c = blockIdx.x;
    const int p = blockIdx.y;
    const int bp = 8 + c;
    const int t = threadIdx.x;
    if (t < PCHUNK) {
        const int i = p * PCHUNK + t;
        const float4 v = boxes[bp * KMAX + i];
        pb[t] = v;
        par[t] = (v.z - v.x) * (v.w - v.y);
        pcls[t] = keep[bp * KMAX + i] ? cls[bp * KMAX + i] : -1;
    }
    __syncthreads();
    const float4 bc = boxes[c * KMAX + t];
    const int cc = cls[c * KMAX + t];
    const float area_c = (bc.z - bc.x) * (bc.w - bc.y);
    float tm = 0.f;
    #pragma unroll 8
    for (int i = 0; i < PCHUNK; ++i) {
        const float4 bi = pb[i];
        const float ax = fmaxf(bi.x, bc.x), ay = fmaxf(bi.y, bc.y);
        const float bx2 = fminf(bi.z, bc.z), by2 = fminf(bi.w, bc.w);
        const float iw = fmaxf(bx2 - ax, 0.f), ih = fmaxf(by2 - ay, 0.f);
        const float inter = iw * ih;
        const float iou = inter / (par[i] + area_c - inter);
        tm = fmaxf(tm, (pcls[i] == cc) ? iou : 0.f);
    }
    pmax[(c * 16 + p) * 256 + t] = tm;
}

// K8b+K9 fused: one block reduces all 8 clean images + writes the scalar
__global__ __launch_bounds__(256) void k_match_final(const float* __restrict__ pmax,
                                                     const int* __restrict__ keep,
                                                     float* __restrict__ out)
{
    __shared__ float red[8];
    const int t = threadIdx.x;
    float tot = 0.f, cn = 0.f;
    for (int c = 0; c < 8; ++c) {
        float tm = 0.f;
        #pragma unroll
        for (int p = 0; p < 16; ++p)
            tm = fmaxf(tm, pmax[(c * 16 + p) * 256 + t]);
        const int kc = keep[c * KMAX + t];
        float val = kc ? tm : 0.f;
        float cv  = kc ? 1.f : 0.f;
        for (int off = 32; off > 0; off >>= 1) {
            val += __shfl_down(val, off);
            cv  += __shfl_down(cv, off);
        }
        const int wv = t >> 6, lane = t & 63;
        if (lane == 0) { red[wv] = val; red[4 + wv] = cv; }
        __syncthreads();
        if (t == 0) {
            tot += red[0] + red[1] + red[2] + red[3];
            cn  += red[4] + red[5] + red[6] + red[7];
        }
        __syncthreads();
    }
    if (t == 0)
        out[0] = (cn > 0.f) ? (1.0f - tot / fmaxf(cn, 1.0f)) : 1.0f;
}

extern "C" void kernel_launch(void* const* d_in, const int* in_sizes, int n_in,
                              void* d_out, int out_size, void* d_ws, size_t ws_size,
                              hipStream_t stream)
{
    if (ws_size < WS_NEED) return;
    const float* clean = (const float*)d_in[0];
    const float* patch = (const float*)d_in[1];
    float* out = (float*)d_out;
    char* ws = (char*)d_ws;

    u64*    keys = (u64*)(ws + OFF_KEYS);
    u64*    mask = (u64*)(ws + OFF_KEYS);   // reuse after k_sort
    int*    hist = (int*)(ws + OFF_HIST);
    int*    ccnt = (int*)(ws + OFF_CCNT);
    u64*    cand = (u64*)(ws + OFF_CAND);
    u64*    diag = (u64*)(ws + OFF_CAND);   // reuse after k_sort
    float*  pmax = (float*)(ws + OFF_CAND); // reuse after k_nms_scan
    u64*    sel  = (u64*)(ws + OFF_SEL);
    float4* boxes = (float4*)(ws + OFF_BOX);
    int*    cls  = (int*)(ws + OFF_CLS);
    u64*    rinit = (u64*)(ws + OFF_RINIT);
    int*    keep = (int*)(ws + OFF_KEEP);

    hipMemsetAsync(ws + OFF_HIST, 0, ZERO_BYTES, stream);

    k_score<<<NIMG * SC4_BPI, 128, 0, stream>>>(clean, patch, keys, hist);
    k_compact<<<dim3(NIMG, 16), 256, 0, stream>>>(keys, hist, ccnt, cand);
    k_sort<<<NIMG, 1024, 0, stream>>>(cand, ccnt, sel);
    k_nms_mask<<<dim3(NIMG, 16), 1024, 0, stream>>>(clean, patch, sel, boxes, cls,
                                                    rinit, mask, diag);
    k_nms_scan<<<NIMG, 1024, KMAX * 16 * 8 + KMAX * 8, stream>>>(mask, diag, rinit, keep);
    k_match_partial<<<dim3(8, 16), 256, 0, stream>>>(boxes, cls, keep, pmax);
    k_match_final<<<1, 256, 0, stream>>>(pmax, keep, out);
}

// Round 17
// 132.276 us; speedup vs baseline: 1.3093x; 1.0005x over previous
//
#include <hip/hip_runtime.h>

#define N_ANCH 25200
#define NCLS   80
#define ROW    85
#define NIMG   16
#define KMAX   1024
#define NBINS  1024
#define CAND_CAP 4096
#define SC2_RPC 16                 // rows per chunk (25200 = 1575*16)
#define SC2_CPI 1575               // chunks per image
#define SC2_CFLOATS (SC2_RPC*ROW)  // 1360 floats = 5440 B = 340 float4 (divides exactly)
#define SC4_BPI 96                 // blocks per image (16*96 = 1536 = 6/CU)
#define SC4_WPI 192                // waves per image
#define PCHUNK 64                  // patch boxes per match block
#define CCNT_STRIDE 16             // ints; one 64B line per image counter

typedef unsigned long long u64;
typedef unsigned int u32;

// ---------------- ws layout (bytes) ----------------
#define OFF_KEYS 0ull                      // 16*25200*8 = 3,225,600 ; mask reuse (2 MB) after k_sort
#define OFF_HIST 3225600ull                // 16*1024*4 = 65,536
#define OFF_CCNT 3291136ull                // 16*64 = 1,024
#define OFF_CAND 3292160ull                // 16*4096*8 = 524,288 ; diag reuse ; pmax reuse
#define OFF_SEL  3816448ull                // 131,072
#define OFF_BOX  3947520ull                // 262,144
#define OFF_CLS  4209664ull                // 65,536
#define OFF_RINIT 4275200ull               // 2,048
#define OFF_KEEP 4277248ull                // 65,536
#define WS_NEED  4342784ull
#define ZERO_BYTES 66560ull                // hist + ccnt contiguous

__device__ __forceinline__ int key_bin(u64 key) {
    u32 hi = (u32)(key >> 32);
    if (hi == 0u) return 0;
    float conf = __uint_as_float(hi - 0x40000000u);
    int b = 1 + (int)(conf * 1022.0f);
    return b > 1023 ? 1023 : b;
}

__device__ __forceinline__ u64 readlane64(u64 v, int src) {
    u32 lo = (u32)__builtin_amdgcn_readlane((int)(u32)(v & 0xffffffffull), src);
    u32 hi = (u32)__builtin_amdgcn_readlane((int)(u32)(v >> 32), src);
    return ((u64)hi << 32) | (u64)lo;
}

__device__ __forceinline__ u64 shfl64_xor(u64 v, int m) {
    int lo = __shfl_xor((int)(u32)(v & 0xffffffffull), m, 64);
    int hi = __shfl_xor((int)(u32)(v >> 32), m, 64);
    return ((u64)(u32)hi << 32) | (u64)(u32)lo;
}

// ---- k_score v8: scalarized register staging + sched_barrier(0) pinning.
// Round 16 proved no-spill (WRITE 7.8 MB) but VGPR=52 showed the compiler
// SANK next-chunk loads to just before their stores (no overlap). The
// sched_barrier(0) after each prefetch pins loads BEFORE the current
// chunk's store+compute, keeping 6 KB/wave in flight during compute.
#define SC_LOAD6(v0, v1, v2, v3, v4, v5, ch) {                                \
    const float4* _s = (const float4*)(img + (size_t)(ch) * SC2_CFLOATS);     \
    v0 = _s[lane];       v1 = _s[lane + 64];  v2 = _s[lane + 128];            \
    v3 = _s[lane + 192]; v4 = _s[lane + 256];                                 \
    if (lane < 20) v5 = _s[lane + 320];                                       \
}
#define SC_STORE6(v0, v1, v2, v3, v4, v5) {                                   \
    float4* _d = (float4*)buf;                                                \
    _d[lane] = v0;       _d[lane + 64] = v1;  _d[lane + 128] = v2;            \
    _d[lane + 192] = v3; _d[lane + 256] = v4;                                 \
    if (lane < 20) _d[lane + 320] = v5;                                       \
}

__device__ __forceinline__ void sc_compute(int b, int c, int lane, const float* buf,
                                           u64* __restrict__ keys, int* bh)
{
    const int r = lane & 15, h = lane >> 4;      // 4 lanes/row, 20 classes each
    const float* p = buf + r * ROW;
    const float obj = p[4];
    float best = -1.0f; int bc = 0;
    #pragma unroll
    for (int d = 0; d < 20; ++d) {
        const float s = p[5 + h * 20 + d] * obj;
        if (s > best) { best = s; bc = h * 20 + d; }
    }
    #pragma unroll
    for (int m = 16; m <= 32; m <<= 1) {
        const float o = __shfl_xor(best, m, 64);
        const int  oc = __shfl_xor(bc, m, 64);
        if (o > best || (o == best && oc < bc)) { best = o; bc = oc; }
    }
    if (h == 0) {
        const int n = c * SC2_RPC + r;
        const float th = (b < 8) ? 0.25f : 0.001f;
        const bool valid = (obj > th) && (best > th);
        const u32 hi = valid ? (__float_as_uint(best) + 0x40000000u) : 0u;
        if (valid) {
            int bin = 1 + (int)(best * 1022.0f);
            if (bin > 1023) bin = 1023;
            atomicAdd(&bh[bin], 1);
        }
        const u32 nbar = 32767u - (u32)n;
        keys[(size_t)b * N_ANCH + n] =
            ((u64)hi << 32) | ((u64)nbar << 8) | (u64)(u32)bc;
    }
}

__global__ __launch_bounds__(128, 3) void k_score(const float* __restrict__ clean,
                                                  const float* __restrict__ patch,
                                                  u64* __restrict__ keys,
                                                  int* __restrict__ hist)
{
    __shared__ float lds[2][SC2_CFLOATS];        // 10,880 B (wave-private bufs)
    __shared__ int bh[NBINS];                    // 4 KB -> 14.9 KB total
    const int t = threadIdx.x;
    const int wv = t >> 6, lane = t & 63;
    const int b = blockIdx.x / SC4_BPI;
    const int blk = blockIdx.x - b * SC4_BPI;
    const int wimg = blk * 2 + wv;               // 0..191
    for (int i = t; i < NBINS; i += 128) bh[i] = 0;
    __syncthreads();
    const float* img = (b < 8) ? clean + (size_t)b * N_ANCH * ROW
                               : patch + (size_t)(b - 8) * N_ANCH * ROW;
    float* buf = &lds[wv][0];
    float4 a0, a1, a2, a3, a4, a5, b0, b1, b2, b3, b4, b5;
    a5 = make_float4(0.f, 0.f, 0.f, 0.f);
    b5 = make_float4(0.f, 0.f, 0.f, 0.f);
    int c = wimg;
    SC_LOAD6(a0, a1, a2, a3, a4, a5, c);
    while (c < SC2_CPI) {
        int cn = c + SC4_WPI;
        if (cn < SC2_CPI) SC_LOAD6(b0, b1, b2, b3, b4, b5, cn);   // next in flight
        __builtin_amdgcn_sched_barrier(0);      // pin: loads issue BEFORE store/compute
        SC_STORE6(a0, a1, a2, a3, a4, a5);                        // waits only on A
        sc_compute(b, c, lane, buf, keys, bh);
        c = cn;
        if (c >= SC2_CPI) break;
        cn = c + SC4_WPI;
        if (cn < SC2_CPI) SC_LOAD6(a0, a1, a2, a3, a4, a5, cn);
        __builtin_amdgcn_sched_barrier(0);
        SC_STORE6(b0, b1, b2, b3, b4, b5);
        sc_compute(b, c, lane, buf, keys, bh);
        c = cn;
    }
    __syncthreads();
    for (int i = t; i < NBINS; i += 128)
        if (bh[i]) atomicAdd(&hist[b * NBINS + i], bh[i]);
}

// K4 (+fused threshold): each block recomputes T from hist via LDS suffix scan,
// then wave-aggregated compaction of its 1575-key stripe.
__global__ __launch_bounds__(256) void k_compact(const u64* __restrict__ keys,
                                                 const int* __restrict__ hist,
                                                 int* __restrict__ ccnt,
                                                 u64* __restrict__ cand)
{
    __shared__ int arr[256];
    __shared__ int Tsh;
    const int b = blockIdx.x;
    const int t = threadIdx.x;
    const int K = (b < 8) ? 256 : 1024;
    int hh[4];
    hh[0] = hist[b * NBINS + 4 * t + 0];
    hh[1] = hist[b * NBINS + 4 * t + 1];
    hh[2] = hist[b * NBINS + 4 * t + 2];
    hh[3] = hist[b * NBINS + 4 * t + 3];
    const int r = hh[0] + hh[1] + hh[2] + hh[3];
    arr[t] = r;
    __syncthreads();
    for (int off = 1; off < 256; off <<= 1) {
        int v = (t + off < 256) ? arr[t + off] : 0;
        __syncthreads();
        arr[t] += v;
        __syncthreads();
    }
    int cb = arr[t] - r;
    for (int d = 3; d >= 0; --d) {
        int ca = cb + hh[d];
        if (cb < K && ca >= K) Tsh = 4 * t + d;   // unique (suffix monotone)
        cb = ca;
    }
    __syncthreads();
    const int T = Tsh;
    const u64* kp = keys + (size_t)b * N_ANCH;
    const int start = blockIdx.y * 1575;
    const int lane = t & 63;
    #pragma unroll
    for (int it = 0; it < 7; ++it) {
        const int off = it * 256 + t;                    // 0..1791
        const bool in = off < 1575;
        const u64 key = in ? kp[start + off] : 0ull;
        const bool cnd = in && (key_bin(key) >= T);
        const u64 bal = __ballot(cnd);
        if (bal) {
            int base = 0;
            if (lane == 0) base = atomicAdd(&ccnt[b * CCNT_STRIDE], __popcll(bal));
            base = __shfl(base, 0, 64);
            if (cnd) {
                const int pos = base + __popcll(bal & ((1ull << lane) - 1ull));
                if (pos < CAND_CAP) cand[(size_t)b * CAND_CAP + pos] = key;
            }
        }
    }
}

// K5: per-image bitonic sort (descending), hybrid register/shuffle/LDS
__global__ __launch_bounds__(1024) void k_sort(const u64* __restrict__ cand,
                                               const int* __restrict__ ccnt,
                                               u64* __restrict__ sel)
{
    __shared__ u64 sk[CAND_CAP];   // 32 KB
    const int b = blockIdx.x;
    const int C = min(ccnt[b * CCNT_STRIDE], CAND_CAP);
    const int t = threadIdx.x;
    u64 e0, e1, e2, e3;
    e0 = (t < C) ? cand[(size_t)b * CAND_CAP + t] : 0ull;
    e1 = (1024 + t < C) ? cand[(size_t)b * CAND_CAP + 1024 + t] : 0ull;
    e2 = (2048 + t < C) ? cand[(size_t)b * CAND_CAP + 2048 + t] : 0ull;
    e3 = (3072 + t < C) ? cand[(size_t)b * CAND_CAP + 3072 + t] : 0ull;
    #define CSWAP_D(a, c) { if ((a) < (c)) { u64 _t = (a); (a) = (c); (c) = _t; } }
    #define CSWAP_A(a, c) { if ((a) > (c)) { u64 _t = (a); (a) = (c); (c) = _t; } }
    for (int k = 2; k <= 4096; k <<= 1) {
        for (int j = k >> 1; j > 0; j >>= 1) {
            if (j >= 1024) {
                if (j == 2048) { CSWAP_D(e0, e2); CSWAP_D(e1, e3); }
                else {
                    if (k == 4096) { CSWAP_D(e0, e1); CSWAP_D(e2, e3); }
                    else           { CSWAP_D(e0, e1); CSWAP_A(e2, e3); }
                }
            } else if (j >= 64) {
                __syncthreads();
                sk[t] = e0; sk[1024 + t] = e1; sk[2048 + t] = e2; sk[3072 + t] = e3;
                __syncthreads();
                const int tp = t ^ j;
                #pragma unroll
                for (int p = 0; p < 4; ++p) {
                    const int i = p * 1024 + t;
                    const u64 cv = (p == 0) ? e0 : (p == 1) ? e1 : (p == 2) ? e2 : e3;
                    const u64 o = sk[p * 1024 + tp];
                    const bool take_max = (((i & k) == 0) == ((t & j) == 0));
                    const u64 mx = cv > o ? cv : o;
                    const u64 mn = cv > o ? o : cv;
                    const u64 nv = take_max ? mx : mn;
                    if (p == 0) e0 = nv; else if (p == 1) e1 = nv;
                    else if (p == 2) e2 = nv; else e3 = nv;
                }
            } else {
                #pragma unroll
                for (int p = 0; p < 4; ++p) {
                    const int i = p * 1024 + t;
                    const u64 cv = (p == 0) ? e0 : (p == 1) ? e1 : (p == 2) ? e2 : e3;
                    const u64 o = shfl64_xor(cv, j);
                    const bool take_max = (((i & k) == 0) == ((t & j) == 0));
                    const u64 mx = cv > o ? cv : o;
                    const u64 mn = cv > o ? o : cv;
                    const u64 nv = take_max ? mx : mn;
                    if (p == 0) e0 = nv; else if (p == 1) e1 = nv;
                    else if (p == 2) e2 = nv; else e3 = nv;
                }
            }
        }
    }
    const int K = (b < 8) ? 256 : 1024;
    if (t < K) sel[b * KMAX + t] = e0;
    #undef CSWAP_D
    #undef CSWAP_A
}

// K6+K7a fused: decode sel -> LDS boxes; y==0 writes boxes/cls/rinit; mask stripe + diag
__global__ __launch_bounds__(1024) void k_nms_mask(const float* __restrict__ clean,
                                                   const float* __restrict__ patch,
                                                   const u64* __restrict__ sel,
                                                   float4* __restrict__ boxes,
                                                   int* __restrict__ cls,
                                                   u64* __restrict__ rinit,
                                                   u64* __restrict__ mask,
                                                   u64* __restrict__ diag)
{
    __shared__ float4 bx[KMAX];
    __shared__ float ar[KMAX];
    const int b = blockIdx.x, y = blockIdx.y;
    const int K = (b < 8) ? 256 : 1024;
    const int row0 = y * 64;
    if (row0 >= K) return;                  // block-uniform
    const int t = threadIdx.x;
    {
        const u64 key = (t < K) ? sel[b * KMAX + t] : 0ull;
        const u32 hi = (u32)(key >> 32);
        const bool valid = (t < K) && (hi != 0u);
        const u64 bal = __ballot(valid);
        if (y == 0 && (t & 63) == 0) rinit[b * 16 + (t >> 6)] = ~bal;
        if (t < K) {
            const int n = 32767 - (int)((key >> 8) & 0x7FFFu);
            const int c = (int)(key & 0x7Fu);
            const float* src = ((b < 8) ? (clean + (size_t)b * N_ANCH * ROW)
                                        : (patch + (size_t)(b - 8) * N_ANCH * ROW))
                               + (size_t)n * ROW;
            const float x = src[0], yy = src[1], w = src[2], h = src[3];
            const float4 raw = make_float4(x - w * 0.5f, yy - h * 0.5f,
                                           x + w * 0.5f, yy + h * 0.5f);
            if (y == 0) { boxes[b * KMAX + t] = raw; cls[b * KMAX + t] = c; }
            const float off = (float)c * 4096.0f;
            const float4 ob = make_float4(raw.x + off, raw.y + off,
                                          raw.z + off, raw.w + off);
            bx[t] = ob;
            ar[t] = (ob.z - ob.x) * (ob.w - ob.y);
        }
    }
    __syncthreads();
    const int w   = t >> 6;
    const int row = row0 + (t & 63);
    u64* dst = mask + ((size_t)b * KMAX + row) * 16 + w;
    if (((w << 6) + 63) <= row0 && row0 > 0) { *dst = 0ull; return; }
    const float4 bi = bx[row];
    const float ai = ar[row];
    const int jbase = w << 6;
    u64 m = 0;
    #pragma unroll 8
    for (int k = 0; k < 64; ++k) {
        const int j = jbase + k;
        const float4 bj = bx[j];
        const float ax = fmaxf(bi.x, bj.x), ay = fmaxf(bi.y, bj.y);
        const float bx2 = fminf(bi.z, bj.z), by2 = fminf(bi.w, bj.w);
        const float iw = fmaxf(bx2 - ax, 0.f), ih = fmaxf(by2 - ay, 0.f);
        const float inter = iw * ih;
        const float iou = inter / (ai + ar[j] - inter);
        if (j > row && iou > 0.45f) m |= (1ull << k);
    }
    *dst = m;
    if (w == (row0 >> 6)) diag[(size_t)b * KMAX + row] = m;
}

// K7b: greedy scan (sparse chain + ILP), one block per image
__global__ __launch_bounds__(1024) void k_nms_scan(const u64* __restrict__ mask,
                                                   const u64* __restrict__ diag,
                                                   const u64* __restrict__ rinit,
                                                   int* __restrict__ keep)
{
    extern __shared__ u64 smem[];           // K*16 mask + K diag
    const int b = blockIdx.x;
    const int K = (b < 8) ? 256 : 1024;
    const int W = K >> 6;
    const int t = threadIdx.x;
    u64* smask = smem;
    u64* sdiag = smem + (size_t)K * 16;
    {
        const float4* s4 = (const float4*)(mask + (size_t)b * KMAX * 16);
        float4* d4 = (float4*)smask;
        const int n4 = (K * 16) >> 1;
        for (int i = t; i < n4; i += 1024) d4[i] = s4[i];
        const float4* s4d = (const float4*)(diag + (size_t)b * KMAX);
        float4* d4d = (float4*)sdiag;
        for (int i = t; i < (K >> 1); i += 1024) d4d[i] = s4d[i];
    }
    __syncthreads();
    if (t >= 64) return;
    const int lane = t;
    const int q = lane >> 4;
    const int wl = lane & 15;
    u64 w_remv = rinit[b * 16 + wl];
    u64 ow = readlane64(w_remv, 0);
    u64 dj = sdiag[lane];
    for (int g = 0; g < W; ++g) {
        u64 nz = __ballot(dj != 0ull);
        u64 o = ow;
        while (nz) {
            const int j = (int)__builtin_ctzll(nz);
            nz &= nz - 1;
            if (!((o >> j) & 1ull)) o |= readlane64(dj, j);
        }
        const u64 kept = ~o;
        if (g + 1 < W) dj = sdiag[(g + 1) * 64 + lane];
        const u64* mrow = smask + (size_t)(g * 64 + q * 16) * 16 + wl;
        const u32 kg = (u32)((kept >> (q * 16)) & 0xFFFFull);
        u64 a0 = 0, a1 = 0;
        #pragma unroll
        for (int i = 0; i < 16; i += 2) {
            const u64 m0 = mrow[(size_t)(i + 0) * 16];
            const u64 m1 = mrow[(size_t)(i + 1) * 16];
            a0 |= ((kg >> i) & 1u) ? m0 : 0ull;
            a1 |= ((kg >> (i + 1)) & 1u) ? m1 : 0ull;
        }
        u64 part = a0 | a1;
        part |= shfl64_xor(part, 16);
        part |= shfl64_xor(part, 32);
        w_remv |= part;
        if (g + 1 < W) ow = readlane64(w_remv, g + 1);
    }
    if (lane < W) {
        #pragma unroll
        for (int k = 0; k < 64; ++k)
            keep[b * KMAX + lane * 64 + k] = (int)(((w_remv >> k) & 1) ^ 1ull);
    }
}

// K8a: partial max IoU: block = (clean image, patch chunk of 64)
__global__ __launch_bounds__(256) void k_match_partial(const float4* __restrict__ boxes,
                                                       const int* __restrict__ cls,
                                                       const int* __restrict__ keep,
                                                       float* __restrict__ pmax)
{
    __shared__ float4 pb[PCHUNK];
    __shared__ float par[PCHUNK];
    __shared__ int pcls[PCHUNK];
    const int c = blockIdx.x;
    const int p = blockIdx.y;
    const int bp = 8 + c;
    const int t = threadIdx.x;
    if (t < PCHUNK) {
        const int i = p * PCHUNK + t;
        const float4 v = boxes[bp * KMAX + i];
        pb[t] = v;
        par[t] = (v.z - v.x) * (v.w - v.y);
        pcls[t] = keep[bp * KMAX + i] ? cls[bp * KMAX + i] : -1;
    }
    __syncthreads();
    const float4 bc = boxes[c * KMAX + t];
    const int cc = cls[c * KMAX + t];
    const float area_c = (bc.z - bc.x) * (bc.w - bc.y);
    float tm = 0.f;
    #pragma unroll 8
    for (int i = 0; i < PCHUNK; ++i) {
        const float4 bi = pb[i];
        const float ax = fmaxf(bi.x, bc.x), ay = fmaxf(bi.y, bc.y);
        const float bx2 = fminf(bi.z, bc.z), by2 = fminf(bi.w, bc.w);
        const float iw = fmaxf(bx2 - ax, 0.f), ih = fmaxf(by2 - ay, 0.f);
        const float inter = iw * ih;
        const float iou = inter / (par[i] + area_c - inter);
        tm = fmaxf(tm, (pcls[i] == cc) ? iou : 0.f);
    }
    pmax[(c * 16 + p) * 256 + t] = tm;
}

// K8b+K9 fused: one block reduces all 8 clean images + writes the scalar
__global__ __launch_bounds__(256) void k_match_final(const float* __restrict__ pmax,
                                                     const int* __restrict__ keep,
                                                     float* __restrict__ out)
{
    __shared__ float red[8];
    const int t = threadIdx.x;
    float tot = 0.f, cn = 0.f;
    for (int c = 0; c < 8; ++c) {
        float tm = 0.f;
        #pragma unroll
        for (int p = 0; p < 16; ++p)
            tm = fmaxf(tm, pmax[(c * 16 + p) * 256 + t]);
        const int kc = keep[c * KMAX + t];
        float val = kc ? tm : 0.f;
        float cv  = kc ? 1.f : 0.f;
        for (int off = 32; off > 0; off >>= 1) {
            val += __shfl_down(val, off);
            cv  += __shfl_down(cv, off);
        }
        const int wv = t >> 6, lane = t & 63;
        if (lane == 0) { red[wv] = val; red[4 + wv] = cv; }
        __syncthreads();
        if (t == 0) {
            tot += red[0] + red[1] + red[2] + red[3];
            cn  += red[4] + red[5] + red[6] + red[7];
        }
        __syncthreads();
    }
    if (t == 0)
        out[0] = (cn > 0.f) ? (1.0f - tot / fmaxf(cn, 1.0f)) : 1.0f;
}

extern "C" void kernel_launch(void* const* d_in, const int* in_sizes, int n_in,
                              void* d_out, int out_size, void* d_ws, size_t ws_size,
                              hipStream_t stream)
{
    if (ws_size < WS_NEED) return;
    const float* clean = (const float*)d_in[0];
    const float* patch = (const float*)d_in[1];
    float* out = (float*)d_out;
    char* ws = (char*)d_ws;

    u64*    keys = (u64*)(ws + OFF_KEYS);
    u64*    mask = (u64*)(ws + OFF_KEYS);   // reuse after k_sort
    int*    hist = (int*)(ws + OFF_HIST);
    int*    ccnt = (int*)(ws + OFF_CCNT);
    u64*    cand = (u64*)(ws + OFF_CAND);
    u64*    diag = (u64*)(ws + OFF_CAND);   // reuse after k_sort
    float*  pmax = (float*)(ws + OFF_CAND); // reuse after k_nms_scan
    u64*    sel  = (u64*)(ws + OFF_SEL);
    float4* boxes = (float4*)(ws + OFF_BOX);
    int*    cls  = (int*)(ws + OFF_CLS);
    u64*    rinit = (u64*)(ws + OFF_RINIT);
    int*    keep = (int*)(ws + OFF_KEEP);

    hipMemsetAsync(ws + OFF_HIST, 0, ZERO_BYTES, stream);

    k_score<<<NIMG * SC4_BPI, 128, 0, stream>>>(clean, patch, keys, hist);
    k_compact<<<dim3(NIMG, 16), 256, 0, stream>>>(keys, hist, ccnt, cand);
    k_sort<<<NIMG, 1024, 0, stream>>>(cand, ccnt, sel);
    k_nms_mask<<<dim3(NIMG, 16), 1024, 0, stream>>>(clean, patch, sel, boxes, cls,
                                                    rinit, mask, diag);
    k_nms_scan<<<NIMG, 1024, KMAX * 16 * 8 + KMAX * 8, stream>>>(mask, diag, rinit, keep);
    k_match_partial<<<dim3(8, 16), 256, 0, stream>>>(boxes, cls, keep, pmax);
    k_match_final<<<1, 256, 0, stream>>>(pmax, keep, out);
}

// Round 18
// 113.138 us; speedup vs baseline: 1.5308x; 1.1692x over previous
//
#include <hip/hip_runtime.h>

#define N_ANCH 25200
#define NCLS   80
#define ROW    85
#define NIMG   16
#define KMAX   1024
#define NBINS  1024
#define CAND_CAP 2048
#define SC2_RPC 16                 // rows per chunk (25200 = 1575*16)
#define SC2_CPI 1575               // chunks per image
#define SC2_CFLOATS (SC2_RPC*ROW)  // 1360 floats = 5440 B = 340 float4
#define SC4_BPI 96                 // blocks per image (16*96 = 1536 = 6/CU)
#define SC4_WPI 192                // waves per image
#define PCHUNK 64                  // patch boxes per match block
#define CCNT_STRIDE 16             // ints; one 64B line per image counter

typedef unsigned long long u64;
typedef unsigned int u32;

// ---------------- ws layout (bytes) ----------------
#define OFF_KEYS 0ull                      // 3,225,600 ; mask reuse (2 MB) after k_sort
#define OFF_HIST 3225600ull                // 65,536
#define OFF_CCNT 3291136ull                // 1,024
#define OFF_CAND 3292160ull                // 16*2048*8 = 262,144 ; diag reuse ; pmax reuse
#define OFF_SEL  3554304ull                // 131,072
#define OFF_BOX  3685376ull                // 262,144
#define OFF_CLS  3947520ull                // 65,536
#define OFF_RINIT 4013056ull               // 2,048
#define OFF_KEEP 4015104ull                // 65,536
#define WS_NEED  4080640ull
#define ZERO_BYTES 66560ull                // hist + ccnt contiguous

__device__ __forceinline__ int key_bin(u64 key) {
    u32 hi = (u32)(key >> 32);
    if (hi == 0u) return 0;
    float conf = __uint_as_float(hi - 0x40000000u);
    int b = 1 + (int)(conf * 1022.0f);
    return b > 1023 ? 1023 : b;
}

__device__ __forceinline__ u64 readlane64(u64 v, int src) {
    u32 lo = (u32)__builtin_amdgcn_readlane((int)(u32)(v & 0xffffffffull), src);
    u32 hi = (u32)__builtin_amdgcn_readlane((int)(u32)(v >> 32), src);
    return ((u64)hi << 32) | (u64)lo;
}

__device__ __forceinline__ u64 shfl64_xor(u64 v, int m) {
    int lo = __shfl_xor((int)(u32)(v & 0xffffffffull), m, 64);
    int hi = __shfl_xor((int)(u32)(v >> 32), m, 64);
    return ((u64)(u32)hi << 32) | (u64)(u32)lo;
}

// ---- k_score (frozen at best measured variant): scalarized reg staging ----
#define SC_LOAD6(v0, v1, v2, v3, v4, v5, ch) {                                \
    const float4* _s = (const float4*)(img + (size_t)(ch) * SC2_CFLOATS);     \
    v0 = _s[lane];       v1 = _s[lane + 64];  v2 = _s[lane + 128];            \
    v3 = _s[lane + 192]; v4 = _s[lane + 256];                                 \
    if (lane < 20) v5 = _s[lane + 320];                                       \
}
#define SC_STORE6(v0, v1, v2, v3, v4, v5) {                                   \
    float4* _d = (float4*)buf;                                                \
    _d[lane] = v0;       _d[lane + 64] = v1;  _d[lane + 128] = v2;            \
    _d[lane + 192] = v3; _d[lane + 256] = v4;                                 \
    if (lane < 20) _d[lane + 320] = v5;                                       \
}

__device__ __forceinline__ void sc_compute(int b, int c, int lane, const float* buf,
                                           u64* __restrict__ keys, int* bh)
{
    const int r = lane & 15, h = lane >> 4;      // 4 lanes/row, 20 classes each
    const float* p = buf + r * ROW;
    const float obj = p[4];
    float best = -1.0f; int bc = 0;
    #pragma unroll
    for (int d = 0; d < 20; ++d) {
        const float s = p[5 + h * 20 + d] * obj;
        if (s > best) { best = s; bc = h * 20 + d; }
    }
    #pragma unroll
    for (int m = 16; m <= 32; m <<= 1) {
        const float o = __shfl_xor(best, m, 64);
        const int  oc = __shfl_xor(bc, m, 64);
        if (o > best || (o == best && oc < bc)) { best = o; bc = oc; }
    }
    if (h == 0) {
        const int n = c * SC2_RPC + r;
        const float th = (b < 8) ? 0.25f : 0.001f;
        const bool valid = (obj > th) && (best > th);
        const u32 hi = valid ? (__float_as_uint(best) + 0x40000000u) : 0u;
        if (valid) {
            int bin = 1 + (int)(best * 1022.0f);
            if (bin > 1023) bin = 1023;
            atomicAdd(&bh[bin], 1);
        }
        const u32 nbar = 32767u - (u32)n;
        keys[(size_t)b * N_ANCH + n] =
            ((u64)hi << 32) | ((u64)nbar << 8) | (u64)(u32)bc;
    }
}

__global__ __launch_bounds__(128, 3) void k_score(const float* __restrict__ clean,
                                                  const float* __restrict__ patch,
                                                  u64* __restrict__ keys,
                                                  int* __restrict__ hist)
{
    __shared__ float lds[2][SC2_CFLOATS];
    __shared__ int bh[NBINS];
    const int t = threadIdx.x;
    const int wv = t >> 6, lane = t & 63;
    const int b = blockIdx.x / SC4_BPI;
    const int blk = blockIdx.x - b * SC4_BPI;
    const int wimg = blk * 2 + wv;
    for (int i = t; i < NBINS; i += 128) bh[i] = 0;
    __syncthreads();
    const float* img = (b < 8) ? clean + (size_t)b * N_ANCH * ROW
                               : patch + (size_t)(b - 8) * N_ANCH * ROW;
    float* buf = &lds[wv][0];
    float4 a0, a1, a2, a3, a4, a5, b0, b1, b2, b3, b4, b5;
    a5 = make_float4(0.f, 0.f, 0.f, 0.f);
    b5 = make_float4(0.f, 0.f, 0.f, 0.f);
    int c = wimg;
    SC_LOAD6(a0, a1, a2, a3, a4, a5, c);
    while (c < SC2_CPI) {
        int cn = c + SC4_WPI;
        if (cn < SC2_CPI) SC_LOAD6(b0, b1, b2, b3, b4, b5, cn);
        __builtin_amdgcn_sched_barrier(0);
        SC_STORE6(a0, a1, a2, a3, a4, a5);
        sc_compute(b, c, lane, buf, keys, bh);
        c = cn;
        if (c >= SC2_CPI) break;
        cn = c + SC4_WPI;
        if (cn < SC2_CPI) SC_LOAD6(a0, a1, a2, a3, a4, a5, cn);
        __builtin_amdgcn_sched_barrier(0);
        SC_STORE6(b0, b1, b2, b3, b4, b5);
        sc_compute(b, c, lane, buf, keys, bh);
        c = cn;
    }
    __syncthreads();
    for (int i = t; i < NBINS; i += 128)
        if (bh[i]) atomicAdd(&hist[b * NBINS + i], bh[i]);
}

// K4 (+fused threshold): per-block T recompute + wave-aggregated compaction
__global__ __launch_bounds__(256) void k_compact(const u64* __restrict__ keys,
                                                 const int* __restrict__ hist,
                                                 int* __restrict__ ccnt,
                                                 u64* __restrict__ cand)
{
    __shared__ int arr[256];
    __shared__ int Tsh;
    const int b = blockIdx.x;
    const int t = threadIdx.x;
    const int K = (b < 8) ? 256 : 1024;
    int hh[4];
    hh[0] = hist[b * NBINS + 4 * t + 0];
    hh[1] = hist[b * NBINS + 4 * t + 1];
    hh[2] = hist[b * NBINS + 4 * t + 2];
    hh[3] = hist[b * NBINS + 4 * t + 3];
    const int r = hh[0] + hh[1] + hh[2] + hh[3];
    arr[t] = r;
    __syncthreads();
    for (int off = 1; off < 256; off <<= 1) {
        int v = (t + off < 256) ? arr[t + off] : 0;
        __syncthreads();
        arr[t] += v;
        __syncthreads();
    }
    int cb = arr[t] - r;
    for (int d = 3; d >= 0; --d) {
        int ca = cb + hh[d];
        if (cb < K && ca >= K) Tsh = 4 * t + d;
        cb = ca;
    }
    __syncthreads();
    const int T = Tsh;
    const u64* kp = keys + (size_t)b * N_ANCH;
    const int start = blockIdx.y * 1575;
    const int lane = t & 63;
    #pragma unroll
    for (int it = 0; it < 7; ++it) {
        const int off = it * 256 + t;
        const bool in = off < 1575;
        const u64 key = in ? kp[start + off] : 0ull;
        const bool cnd = in && (key_bin(key) >= T);
        const u64 bal = __ballot(cnd);
        if (bal) {
            int base = 0;
            if (lane == 0) base = atomicAdd(&ccnt[b * CCNT_STRIDE], __popcll(bal));
            base = __shfl(base, 0, 64);
            if (cnd) {
                const int pos = base + __popcll(bal & ((1ull << lane) - 1ull));
                if (pos < CAND_CAP) cand[(size_t)b * CAND_CAP + pos] = key;
            }
        }
    }
}

// K5: bitonic sort over 2048 (2 elems/thread) + decode tail (sel/boxes/cls/rinit)
__global__ __launch_bounds__(1024) void k_sort(const u64* __restrict__ cand,
                                               const int* __restrict__ ccnt,
                                               const float* __restrict__ clean,
                                               const float* __restrict__ patch,
                                               u64* __restrict__ sel,
                                               float4* __restrict__ boxes,
                                               int* __restrict__ cls,
                                               u64* __restrict__ rinit)
{
    __shared__ u64 sk[CAND_CAP];   // 16 KB
    const int b = blockIdx.x;
    const int C = min(ccnt[b * CCNT_STRIDE], CAND_CAP);
    const int t = threadIdx.x;
    u64 e0 = (t < C) ? cand[(size_t)b * CAND_CAP + t] : 0ull;
    u64 e1 = (1024 + t < C) ? cand[(size_t)b * CAND_CAP + 1024 + t] : 0ull;
    for (int k = 2; k <= 2048; k <<= 1) {
        for (int j = k >> 1; j > 0; j >>= 1) {
            if (j == 1024) {                 // k==2048: desc everywhere
                if (e0 < e1) { u64 tmp = e0; e0 = e1; e1 = tmp; }
            } else if (j >= 64) {
                __syncthreads();
                sk[t] = e0; sk[1024 + t] = e1;
                __syncthreads();
                const int tp = t ^ j;
                #pragma unroll
                for (int p = 0; p < 2; ++p) {
                    const int i = p * 1024 + t;
                    const u64 cv = (p == 0) ? e0 : e1;
                    const u64 o = sk[p * 1024 + tp];
                    const bool take_max = (((i & k) == 0) == ((t & j) == 0));
                    const u64 mx = cv > o ? cv : o;
                    const u64 mn = cv > o ? o : cv;
                    const u64 nv = take_max ? mx : mn;
                    if (p == 0) e0 = nv; else e1 = nv;
                }
            } else {
                #pragma unroll
                for (int p = 0; p < 2; ++p) {
                    const int i = p * 1024 + t;
                    const u64 cv = (p == 0) ? e0 : e1;
                    const u64 o = shfl64_xor(cv, j);
                    const bool take_max = (((i & k) == 0) == ((t & j) == 0));
                    const u64 mx = cv > o ? cv : o;
                    const u64 mn = cv > o ? o : cv;
                    const u64 nv = take_max ? mx : mn;
                    if (p == 0) e0 = nv; else e1 = nv;
                }
            }
        }
    }
    const int K = (b < 8) ? 256 : 1024;
    // decode tail: sel, rinit ballot, boxes, cls (once per image; mask blocks
    // previously re-decoded scattered rows 16x redundantly)
    const u32 hi = (u32)(e0 >> 32);
    const bool valid = (t < K) && (hi != 0u);
    const u64 bal = __ballot(valid);
    if ((t & 63) == 0) rinit[b * 16 + (t >> 6)] = ~bal;
    if (t < K) {
        sel[b * KMAX + t] = e0;
        const int n = 32767 - (int)((e0 >> 8) & 0x7FFFu);
        const int c = (int)(e0 & 0x7Fu);
        const float* src = ((b < 8) ? (clean + (size_t)b * N_ANCH * ROW)
                                    : (patch + (size_t)(b - 8) * N_ANCH * ROW))
                           + (size_t)n * ROW;
        const float x = src[0], y = src[1], w = src[2], h = src[3];
        boxes[b * KMAX + t] = make_float4(x - w * 0.5f, y - h * 0.5f,
                                          x + w * 0.5f, y + h * 0.5f);
        cls[b * KMAX + t] = c;
    }
}

// K7a: mask stripe + diag; boxes/cls read coalesced (decoded once in k_sort)
__global__ __launch_bounds__(1024) void k_nms_mask(const float4* __restrict__ boxes,
                                                   const int* __restrict__ cls,
                                                   u64* __restrict__ mask,
                                                   u64* __restrict__ diag)
{
    __shared__ float4 bx[KMAX];
    __shared__ float ar[KMAX];
    const int b = blockIdx.x, y = blockIdx.y;
    const int K = (b < 8) ? 256 : 1024;
    const int row0 = y * 64;
    if (row0 >= K) return;                  // block-uniform
    const int t = threadIdx.x;
    if (t < K) {
        const float4 raw = boxes[b * KMAX + t];
        const float off = (float)cls[b * KMAX + t] * 4096.0f;
        const float4 ob = make_float4(raw.x + off, raw.y + off,
                                      raw.z + off, raw.w + off);
        bx[t] = ob;
        ar[t] = (ob.z - ob.x) * (ob.w - ob.y);
    }
    __syncthreads();
    const int w   = t >> 6;
    const int row = row0 + (t & 63);
    u64* dst = mask + ((size_t)b * KMAX + row) * 16 + w;
    if (((w << 6) + 63) <= row0 && row0 > 0) { *dst = 0ull; return; }
    const float4 bi = bx[row];
    const float ai = ar[row];
    const int jbase = w << 6;
    u64 m = 0;
    #pragma unroll 8
    for (int k = 0; k < 64; ++k) {
        const int j = jbase + k;
        const float4 bj = bx[j];
        const float ax = fmaxf(bi.x, bj.x), ay = fmaxf(bi.y, bj.y);
        const float bx2 = fminf(bi.z, bj.z), by2 = fminf(bi.w, bj.w);
        const float iw = fmaxf(bx2 - ax, 0.f), ih = fmaxf(by2 - ay, 0.f);
        const float inter = iw * ih;
        const float iou = inter / (ai + ar[j] - inter);
        if (j > row && iou > 0.45f) m |= (1ull << k);
    }
    *dst = m;
    if (w == (row0 >> 6)) diag[(size_t)b * KMAX + row] = m;
}

// K7b: greedy scan (sparse chain + ILP), one block per image
__global__ __launch_bounds__(1024) void k_nms_scan(const u64* __restrict__ mask,
                                                   const u64* __restrict__ diag,
                                                   const u64* __restrict__ rinit,
                                                   int* __restrict__ keep)
{
    extern __shared__ u64 smem[];           // K*16 mask + K diag
    const int b = blockIdx.x;
    const int K = (b < 8) ? 256 : 1024;
    const int W = K >> 6;
    const int t = threadIdx.x;
    u64* smask = smem;
    u64* sdiag = smem + (size_t)K * 16;
    {
        const float4* s4 = (const float4*)(mask + (size_t)b * KMAX * 16);
        float4* d4 = (float4*)smask;
        const int n4 = (K * 16) >> 1;
        for (int i = t; i < n4; i += 1024) d4[i] = s4[i];
        const float4* s4d = (const float4*)(diag + (size_t)b * KMAX);
        float4* d4d = (float4*)sdiag;
        for (int i = t; i < (K >> 1); i += 1024) d4d[i] = s4d[i];
    }
    __syncthreads();
    if (t >= 64) return;
    const int lane = t;
    const int q = lane >> 4;
    const int wl = lane & 15;
    u64 w_remv = rinit[b * 16 + wl];
    u64 ow = readlane64(w_remv, 0);
    u64 dj = sdiag[lane];
    for (int g = 0; g < W; ++g) {
        u64 nz = __ballot(dj != 0ull);
        u64 o = ow;
        while (nz) {
            const int j = (int)__builtin_ctzll(nz);
            nz &= nz - 1;
            if (!((o >> j) & 1ull)) o |= readlane64(dj, j);
        }
        const u64 kept = ~o;
        if (g + 1 < W) dj = sdiag[(g + 1) * 64 + lane];
        const u64* mrow = smask + (size_t)(g * 64 + q * 16) * 16 + wl;
        const u32 kg = (u32)((kept >> (q * 16)) & 0xFFFFull);
        u64 a0 = 0, a1 = 0;
        #pragma unroll
        for (int i = 0; i < 16; i += 2) {
            const u64 m0 = mrow[(size_t)(i + 0) * 16];
            const u64 m1 = mrow[(size_t)(i + 1) * 16];
            a0 |= ((kg >> i) & 1u) ? m0 : 0ull;
            a1 |= ((kg >> (i + 1)) & 1u) ? m1 : 0ull;
        }
        u64 part = a0 | a1;
        part |= shfl64_xor(part, 16);
        part |= shfl64_xor(part, 32);
        w_remv |= part;
        if (g + 1 < W) ow = readlane64(w_remv, g + 1);
    }
    if (lane < W) {
        #pragma unroll
        for (int k = 0; k < 64; ++k)
            keep[b * KMAX + lane * 64 + k] = (int)(((w_remv >> k) & 1) ^ 1ull);
    }
}

// K8a: partial max IoU: block = (clean image, patch chunk of 64)
__global__ __launch_bounds__(256) void k_match_partial(const float4* __restrict__ boxes,
                                                       const int* __restrict__ cls,
                                                       const int* __restrict__ keep,
                                                       float* __restrict__ pmax)
{
    __shared__ float4 pb[PCHUNK];
    __shared__ float par[PCHUNK];
    __shared__ int pcls[PCHUNK];
    const int c = blockIdx.x;
    const int p = blockIdx.y;
    const int bp = 8 + c;
    const int t = threadIdx.x;
    if (t < PCHUNK) {
        const int i = p * PCHUNK + t;
        const float4 v = boxes[bp * KMAX + i];
        pb[t] = v;
        par[t] = (v.z - v.x) * (v.w - v.y);
        pcls[t] = keep[bp * KMAX + i] ? cls[bp * KMAX + i] : -1;
    }
    __syncthreads();
    const float4 bc = boxes[c * KMAX + t];
    const int cc = cls[c * KMAX + t];
    const float area_c = (bc.z - bc.x) * (bc.w - bc.y);
    float tm = 0.f;
    #pragma unroll 8
    for (int i = 0; i < PCHUNK; ++i) {
        const float4 bi = pb[i];
        const float ax = fmaxf(bi.x, bc.x), ay = fmaxf(bi.y, bc.y);
        const float bx2 = fminf(bi.z, bc.z), by2 = fminf(bi.w, bc.w);
        const float iw = fmaxf(bx2 - ax, 0.f), ih = fmaxf(by2 - ay, 0.f);
        const float inter = iw * ih;
        const float iou = inter / (par[i] + area_c - inter);
        tm = fmaxf(tm, (pcls[i] == cc) ? iou : 0.f);
    }
    pmax[(c * 16 + p) * 256 + t] = tm;
}

// K8b+K9 fused: one block reduces all 8 clean images + writes the scalar
__global__ __launch_bounds__(256) void k_match_final(const float* __restrict__ pmax,
                                                     const int* __restrict__ keep,
                                                     float* __restrict__ out)
{
    __shared__ float red[8];
    const int t = threadIdx.x;
    float tot = 0.f, cn = 0.f;
    for (int c = 0; c < 8; ++c) {
        float tm = 0.f;
        #pragma unroll
        for (int p = 0; p < 16; ++p)
            tm = fmaxf(tm, pmax[(c * 16 + p) * 256 + t]);
        const int kc = keep[c * KMAX + t];
        float val = kc ? tm : 0.f;
        float cv  = kc ? 1.f : 0.f;
        for (int off = 32; off > 0; off >>= 1) {
            val += __shfl_down(val, off);
            cv  += __shfl_down(cv, off);
        }
        const int wv = t >> 6, lane = t & 63;
        if (lane == 0) { red[wv] = val; red[4 + wv] = cv; }
        __syncthreads();
        if (t == 0) {
            tot += red[0] + red[1] + red[2] + red[3];
            cn  += red[4] + red[5] + red[6] + red[7];
        }
        __syncthreads();
    }
    if (t == 0)
        out[0] = (cn > 0.f) ? (1.0f - tot / fmaxf(cn, 1.0f)) : 1.0f;
}

extern "C" void kernel_launch(void* const* d_in, const int* in_sizes, int n_in,
                              void* d_out, int out_size, void* d_ws, size_t ws_size,
                              hipStream_t stream)
{
    if (ws_size < WS_NEED) return;
    const float* clean = (const float*)d_in[0];
    const float* patch = (const float*)d_in[1];
    float* out = (float*)d_out;
    char* ws = (char*)d_ws;

    u64*    keys = (u64*)(ws + OFF_KEYS);
    u64*    mask = (u64*)(ws + OFF_KEYS);   // reuse after k_sort
    int*    hist = (int*)(ws + OFF_HIST);
    int*    ccnt = (int*)(ws + OFF_CCNT);
    u64*    cand = (u64*)(ws + OFF_CAND);
    u64*    diag = (u64*)(ws + OFF_CAND);   // reuse after k_sort
    float*  pmax = (float*)(ws + OFF_CAND); // reuse after k_nms_scan
    u64*    sel  = (u64*)(ws + OFF_SEL);
    float4* boxes = (float4*)(ws + OFF_BOX);
    int*    cls  = (int*)(ws + OFF_CLS);
    u64*    rinit = (u64*)(ws + OFF_RINIT);
    int*    keep = (int*)(ws + OFF_KEEP);

    hipMemsetAsync(ws + OFF_HIST, 0, ZERO_BYTES, stream);

    k_score<<<NIMG * SC4_BPI, 128, 0, stream>>>(clean, patch, keys, hist);
    k_compact<<<dim3(NIMG, 16), 256, 0, stream>>>(keys, hist, ccnt, cand);
    k_sort<<<NIMG, 1024, 0, stream>>>(cand, ccnt, clean, patch, sel, boxes, cls, rinit);
    k_nms_mask<<<dim3(NIMG, 16), 1024, 0, stream>>>(boxes, cls, mask, diag);
    k_nms_scan<<<NIMG, 1024, KMAX * 16 * 8 + KMAX * 8, stream>>>(mask, diag, rinit, keep);
    k_match_partial<<<dim3(8, 16), 256, 0, stream>>>(boxes, cls, keep, pmax);
    k_match_final<<<1, 256, 0, stream>>>(pmax, keep, out);
}